// Round 1
// baseline (9844.207 us; speedup 1.0000x reference)
//
#include <hip/hip_runtime.h>
#include <math.h>
#include <limits.h>

#define BATCH 8
#define BEAM 4
#define VOCAB 32000
#define DMODEL 1024
#define MAXSEQ 32
#define PAD_ID 0
#define BOS_ID 1
#define EOS_ID 2
#define NEG_INF_F (-1e9f)
#define NROWS 32        // BATCH*BEAM
#define CTHREADS 512

// ---------------- workspace layout (bytes) ----------------
// hT      : [DMODEL][NROWS] f32      @ 0          (131072 B)
// logits  : [NROWS][VOCAB]  f32      @ 131072     (4096000 B)
// state   : @ 4227072
//   seqs     int[BATCH*BEAM*MAXSEQ]  (4096 B)
//   scores   f32[NROWS]              (+4096)
//   finished int[NROWS]              (+4224)
//   lengths  f32[NROWS]              (+4352)
//   last_tok int[NROWS]              (+4480)
#define HT_OFF      0
#define LOGITS_OFF  131072
#define STATE_OFF   4227072

__device__ __forceinline__ bool better(float av, int ai, float bv, int bi) {
  return (av > bv) || ((av == bv) && (ai < bi));
}

__device__ __forceinline__ void ins4(float v, int i, float tv[4], int ti[4]) {
  if (better(v, i, tv[3], ti[3])) {
    tv[3] = v; ti[3] = i;
    #pragma unroll
    for (int j = 3; j > 0; j--) {
      if (better(tv[j], ti[j], tv[j-1], ti[j-1])) {
        float fv = tv[j]; tv[j] = tv[j-1]; tv[j-1] = fv;
        int ii = ti[j]; ti[j] = ti[j-1]; ti[j-1] = ii;
      }
    }
  }
}

// ---- kernel A: hT[c*32+r] = tanh(emb[tok_r] . Wdec[:,c] + b[c]) ----
// grid (DMODEL/64, nrows/2), block 64
template<bool INIT>
__global__ __launch_bounds__(64) void k_embdec(
    const float* __restrict__ emb, const float* __restrict__ Wdec,
    const float* __restrict__ bdec, const int* __restrict__ last_tok,
    float* __restrict__ hT) {
  int c  = blockIdx.x * 64 + threadIdx.x;
  int r0 = blockIdx.y * 2;
  int t0 = INIT ? BOS_ID : last_tok[r0];
  int t1 = INIT ? BOS_ID : last_tok[r0 + 1];
  const float* x0 = emb + (size_t)t0 * DMODEL;
  const float* x1 = emb + (size_t)t1 * DMODEL;
  float a0 = 0.f, a1 = 0.f;
  #pragma unroll 8
  for (int j = 0; j < DMODEL; j++) {
    float w = Wdec[j * DMODEL + c];
    a0 = fmaf(x0[j], w, a0);
    a1 = fmaf(x1[j], w, a1);
  }
  float bb = bdec[c];
  hT[c * NROWS + r0]     = tanhf(a0 + bb);
  hT[c * NROWS + r0 + 1] = tanhf(a1 + bb);
}

// ---- kernel B: logits[r][c] = sum_k hT[k][r] * Wout[k][c] ----
// grid (VOCAB/64, ngroups), block 64; hT reads are wave-uniform -> scalar loads
template<int RPG>
__global__ __launch_bounds__(64) void k_logits(
    const float* __restrict__ hT, const float* __restrict__ Wout,
    float* __restrict__ logits) {
  int c = blockIdx.x * 64 + threadIdx.x;
  int rbase = blockIdx.y * RPG;
  float acc[RPG];
  #pragma unroll
  for (int r = 0; r < RPG; r++) acc[r] = 0.f;
  #pragma unroll 4
  for (int k = 0; k < DMODEL; k++) {
    float w = Wout[k * VOCAB + c];
    #pragma unroll
    for (int r = 0; r < RPG; r++)
      acc[r] = fmaf(hT[k * NROWS + rbase + r], w, acc[r]);
  }
  #pragma unroll
  for (int r = 0; r < RPG; r++)
    logits[(rbase + r) * VOCAB + c] = acc[r];
}

// ---- kernel C: per-batch LSE + top-4 + beam state update ----
// grid BATCH, block CTHREADS
template<bool INIT>
__global__ __launch_bounds__(CTHREADS) void k_select(
    const float* __restrict__ logits,
    int* __restrict__ seqs, float* __restrict__ scores,
    int* __restrict__ finished, float* __restrict__ lengths,
    int* __restrict__ last_tok, int t, int wout, float* __restrict__ out) {
  __shared__ float s_red[8];
  __shared__ float s_lse;
  __shared__ float s_wv[8][4];
  __shared__ int   s_wi[8][4];
  __shared__ float s_rv[BEAM][4];
  __shared__ int   s_ri[BEAM][4];
  __shared__ float s_score[BEAM];
  __shared__ int   s_beam[BEAM];
  __shared__ int   s_tok[BEAM];

  int b = blockIdx.x;
  int tid = threadIdx.x;
  int lane = tid & 63;
  int wv = tid >> 6;
  const int R = INIT ? 1 : BEAM;

  for (int kk = 0; kk < R; kk++) {
    int row = INIT ? b : b * BEAM + kk;
    bool fin = INIT ? false : (finished[row] != 0);   // block-uniform
    if (!fin) {
      const float* L = logits + (size_t)row * VOCAB;
      // --- row max ---
      float m = -INFINITY;
      for (int c2 = tid; c2 < VOCAB; c2 += CTHREADS) m = fmaxf(m, L[c2]);
      #pragma unroll
      for (int off = 32; off >= 1; off >>= 1) m = fmaxf(m, __shfl_xor(m, off));
      if (lane == 0) s_red[wv] = m;
      __syncthreads();
      if (tid == 0) {
        float mm = s_red[0];
        for (int i = 1; i < 8; i++) mm = fmaxf(mm, s_red[i]);
        s_red[0] = mm;
      }
      __syncthreads();
      float rowmax = s_red[0];
      __syncthreads();
      // --- sum exp ---
      float s = 0.f;
      for (int c2 = tid; c2 < VOCAB; c2 += CTHREADS) s += expf(L[c2] - rowmax);
      #pragma unroll
      for (int off = 32; off >= 1; off >>= 1) s += __shfl_xor(s, off);
      if (lane == 0) s_red[wv] = s;
      __syncthreads();
      if (tid == 0) {
        float ss = 0.f;
        for (int i = 0; i < 8; i++) ss += s_red[i];
        s_lse = rowmax + logf(ss);
      }
      __syncthreads();
      float lse = s_lse;
      float base = INIT ? 0.f : scores[row];
      // --- local top4 of cand = base + (logit - lse) ---
      float tv[4] = {-INFINITY, -INFINITY, -INFINITY, -INFINITY};
      int   ti[4] = {INT_MAX, INT_MAX, INT_MAX, INT_MAX};
      for (int c2 = tid; c2 < VOCAB; c2 += CTHREADS)
        ins4(base + (L[c2] - lse), c2, tv, ti);
      // --- wave top4: 4 rounds of butterfly argmax with pop ---
      int p = 0;
      float wrv[4]; int wri[4];
      #pragma unroll
      for (int r4 = 0; r4 < 4; r4++) {
        float cv = tv[p]; int ci = ti[p];
        #pragma unroll
        for (int off = 32; off >= 1; off >>= 1) {
          float ov = __shfl_xor(cv, off);
          int   oi = __shfl_xor(ci, off);
          if (better(ov, oi, cv, ci)) { cv = ov; ci = oi; }
        }
        if (ti[p] == ci) p++;
        wrv[r4] = cv; wri[r4] = ci;
      }
      if (lane == 0) {
        #pragma unroll
        for (int i = 0; i < 4; i++) { s_wv[wv][i] = wrv[i]; s_wi[wv][i] = wri[i]; }
      }
      __syncthreads();
      if (tid == 0) {
        float bv[4] = {-INFINITY,-INFINITY,-INFINITY,-INFINITY};
        int   bi4[4] = {INT_MAX,INT_MAX,INT_MAX,INT_MAX};
        for (int w = 0; w < 8; w++)
          for (int i = 0; i < 4; i++) ins4(s_wv[w][i], s_wi[w][i], bv, bi4);
        for (int i = 0; i < 4; i++) { s_rv[kk][i] = bv[i]; s_ri[kk][i] = bi4[i]; }
      }
      __syncthreads();
    } else {
      // finished row: pad_row candidates, generated directly
      if (tid == 0) {
        float sc = scores[row];
        s_rv[kk][0] = sc;             s_ri[kk][0] = 0;  // PAD at zero cost
        s_rv[kk][1] = sc + NEG_INF_F; s_ri[kk][1] = 1;
        s_rv[kk][2] = sc + NEG_INF_F; s_ri[kk][2] = 2;
        s_rv[kk][3] = sc + NEG_INF_F; s_ri[kk][3] = 3;
      }
      __syncthreads();
    }
  }

  // --- merge R rows' top4 -> batch top4 (flat idx = kk*V + v, jax tie-break) ---
  if (tid == 0) {
    float fv[4] = {-INFINITY,-INFINITY,-INFINITY,-INFINITY};
    int   fi4[4] = {INT_MAX,INT_MAX,INT_MAX,INT_MAX};
    for (int kk = 0; kk < R; kk++)
      for (int i = 0; i < 4; i++)
        ins4(s_rv[kk][i], kk * VOCAB + s_ri[kk][i], fv, fi4);
    for (int i = 0; i < 4; i++) {
      s_score[i] = fv[i];
      s_beam[i]  = fi4[i] / VOCAB;
      s_tok[i]   = fi4[i] % VOCAB;
    }
  }
  __syncthreads();

  // --- state update (read old, barrier, write new) ---
  int k5 = tid >> 5, p5 = tid & 31;
  int sv = 0, oldfin = 0; float oldlen = 0.f;
  if (!INIT) {
    if (tid < 128) {
      sv = seqs[(b * BEAM + s_beam[k5]) * MAXSEQ + p5];
      if (p5 == t) sv = s_tok[k5];
    }
    if (tid < 4) {
      oldfin = finished[b * BEAM + s_beam[tid]];
      oldlen = lengths[b * BEAM + s_beam[tid]];
    }
  }
  __syncthreads();
  if (INIT) {
    if (tid < 128) {
      int val = (p5 == 0) ? BOS_ID : ((p5 == 1) ? s_tok[k5] : PAD_ID);
      seqs[(b * BEAM + k5) * MAXSEQ + p5] = val;
    }
    if (tid < 4) {
      scores[b * BEAM + tid]   = s_score[tid];
      finished[b * BEAM + tid] = (s_tok[tid] == EOS_ID) ? 1 : 0;
      lengths[b * BEAM + tid]  = 1.f;
      last_tok[b * BEAM + tid] = s_tok[tid];
    }
  } else {
    if (tid < 128) {
      seqs[(b * BEAM + k5) * MAXSEQ + p5] = sv;
      if (wout) out[(b * BEAM + k5) * MAXSEQ + p5] = (float)sv;
    }
    if (tid < 4) {
      float nl = oldlen + (oldfin ? 0.f : 1.f);
      int   nf = (oldfin || (s_tok[tid] == EOS_ID)) ? 1 : 0;
      scores[b * BEAM + tid]   = s_score[tid];
      finished[b * BEAM + tid] = nf;
      lengths[b * BEAM + tid]  = nl;
      last_tok[b * BEAM + tid] = s_tok[tid];
      if (wout)
        out[BATCH * BEAM * MAXSEQ + b * BEAM + tid] =
            s_score[tid] / powf((5.f + nl) / 6.f, 0.6f);
    }
  }
}

extern "C" void kernel_launch(void* const* d_in, const int* in_sizes, int n_in,
                              void* d_out, int out_size, void* d_ws, size_t ws_size,
                              hipStream_t stream) {
  const float* emb  = (const float*)d_in[0];
  const float* Wdec = (const float*)d_in[1];
  const float* bdec = (const float*)d_in[2];
  const float* Wout = (const float*)d_in[3];
  float* out = (float*)d_out;

  char* ws = (char*)d_ws;
  float* hT       = (float*)(ws + HT_OFF);
  float* logits   = (float*)(ws + LOGITS_OFF);
  int*   seqs     = (int*)  (ws + STATE_OFF);
  float* scores   = (float*)(ws + STATE_OFF + 4096);
  int*   finished = (int*)  (ws + STATE_OFF + 4224);
  float* lengths  = (float*)(ws + STATE_OFF + 4352);
  int*   last_tok = (int*)  (ws + STATE_OFF + 4480);

  // ---- initial step from <bos> (8 rows) ----
  k_embdec<true><<<dim3(DMODEL / 64, BATCH / 2), 64, 0, stream>>>(
      emb, Wdec, bdec, last_tok, hT);
  k_logits<8><<<dim3(VOCAB / 64, 1), 64, 0, stream>>>(hT, Wout, logits);
  k_select<true><<<BATCH, CTHREADS, 0, stream>>>(
      logits, seqs, scores, finished, lengths, last_tok, 0, 0, out);

  // ---- decode steps t = 2..31 (32 rows each) ----
  for (int t = 2; t < MAXSEQ; t++) {
    k_embdec<false><<<dim3(DMODEL / 64, NROWS / 2), 64, 0, stream>>>(
        emb, Wdec, bdec, last_tok, hT);
    k_logits<16><<<dim3(VOCAB / 64, 2), 64, 0, stream>>>(hT, Wout, logits);
    k_select<false><<<BATCH, CTHREADS, 0, stream>>>(
        logits, seqs, scores, finished, lengths, last_tok, t,
        (t == MAXSEQ - 1) ? 1 : 0, out);
  }
}